// Round 1
// baseline (301.875 us; speedup 1.0000x reference)
//
#include <hip/hip_runtime.h>

// CustomConvolve: locally-connected 2x2 conv, unshared weights.
// x: [B=16, C=16, W=512, H=512] f32
// weights: [(W-1)*(H-1), 4] f32, bias: [(W-1)*(H-1)] f32
// out: [B, C, 511, 511] f32; out[:, :, 0, :] = out[:, :, :, 0] = 0.
// neuron index 511*w + h == flat in-plane output index -> coalesced.

constexpr int W = 512;
constexpr int H = 512;
constexpr int OW = W - 1;               // 511
constexpr int OH = H - 1;               // 511
constexpr int PLANE_OUT = OW * OH;      // 261121
constexpr int PLANE_IN  = W * H;        // 262144

__global__ __launch_bounds__(256)
void lc_conv2x2(const float* __restrict__ x,
                const float4* __restrict__ weights,
                const float* __restrict__ bias,
                float* __restrict__ out) {
    int gid = blockIdx.x * 256 + threadIdx.x;   // flat in-plane output index
    if (gid >= PLANE_OUT) return;
    int plane = blockIdx.y;                     // b*c plane, 0..255

    int w = gid / OH;                           // compiler: magic-mul division
    int h = gid - w * OH;

    float* outp = out + (size_t)plane * PLANE_OUT;
    if (w == 0 || h == 0) {
        outp[gid] = 0.0f;                       // must be written every launch
        return;
    }

    const float* xp = x + (size_t)plane * PLANE_IN;
    const float* r0 = xp + (w - 1) * H + (h - 1);   // row w-1, col h-1
    const float* r1 = xp + w * H + (h - 1);         // row w,   col h-1

    float4 wt = weights[gid];
    float  bv = bias[gid];

    float v = r0[0] * wt.x + r0[1] * wt.y + r1[0] * wt.z + r1[1] * wt.w + bv;
    outp[gid] = v;
}

extern "C" void kernel_launch(void* const* d_in, const int* in_sizes, int n_in,
                              void* d_out, int out_size, void* d_ws, size_t ws_size,
                              hipStream_t stream) {
    const float*  x       = (const float*)d_in[0];
    const float4* weights = (const float4*)d_in[1];
    const float*  bias    = (const float*)d_in[2];
    float*        out     = (float*)d_out;

    int planes = in_sizes[0] / PLANE_IN;        // B*C = 256
    dim3 grid((PLANE_OUT + 255) / 256, planes);
    lc_conv2x2<<<grid, 256, 0, stream>>>(x, weights, bias, out);
}

// Round 2
// 224.517 us; speedup vs baseline: 1.3446x; 1.3446x over previous
//
#include <hip/hip_runtime.h>

// Locally-connected 2x2 conv, unshared weights.
// x: [256 planes, 512, 512] f32; weights: [511*511, 4]; bias: [511*511]
// out: [256, 511, 511]; out row 0 / col 0 are zero.
// neuron index = 511*w + h == flat in-plane output index.

constexpr int W = 512;
constexpr int H = 512;
constexpr int OW = 511;
constexpr int OH = 511;
constexpr int PLANE_OUT = OW * OH;      // 261121
constexpr int PLANE_IN  = W * H;        // 262144
constexpr int PPG = 16;                 // planes per group (register-weight reuse)

// Block tile: 8 output rows x 256 output cols; 256 threads; each thread 2x4.
// Row tiles: 64 (rows 1..510+, last partial). Col tiles: 2 (cols 1..256, 257..510).

__global__ __launch_bounds__(256)
void lc_conv2x2_v2(const float* __restrict__ x,
                   const float* __restrict__ weights,
                   const float* __restrict__ bias,
                   float* __restrict__ out,
                   int planes) {
    const int tid    = threadIdx.x;
    const int lane_h = tid & 63;        // 64 threads across h
    const int lane_w = tid >> 6;        // 4 threads across w (2 rows each)

    const int tc = blockIdx.x & 1;      // col tile
    const int tw = blockIdx.x >> 1;     // row tile

    const int h0 = 1 + (tc << 8) + (lane_h << 2);   // first of 4 cols (h0-1 % 4 == 0)
    const int w0 = 1 + (tw << 3) + (lane_w << 1);   // first of 2 rows
    const int w1 = w0 + 1;

    const bool wv0 = (w0 <= 510);
    const bool wv1 = (w1 <= 510);

    // ---- weights + bias into registers (clamped gid; invalid lanes masked at store)
    float4 wt[2][4];
    float  bv[2][4];
    #pragma unroll
    for (int r = 0; r < 2; ++r) {
        int wr = min(w0 + r, 510);
        #pragma unroll
        for (int j = 0; j < 4; ++j) {
            int hh  = min(h0 + j, 510);
            int gid = wr * OH + hh;
            wt[r][j] = *(const float4*)(weights + 4 * (size_t)gid);
            bv[r][j] = bias[gid];
        }
    }

    // x rows needed: w0-1, w0, w0+1 (clamped: last tile's masked rows)
    const int xr0 = w0 - 1;             // >= 0 always
    const int xr1 = min(w0, 511);
    const int xr2 = min(w1, 511);
    const int hx  = h0 - 1;             // 16B-aligned column start
    const int hx4 = min(hx + 4, 511);   // clamp the +4 scalar (unused when masked)

    const int p0 = blockIdx.y * PPG;
    const int p1 = min(p0 + PPG, planes);

    for (int p = p0; p < p1; ++p) {
        const float* xp = x + (size_t)p * PLANE_IN;

        float4 a0 = *(const float4*)(xp + xr0 * H + hx);
        float  a4 = xp[xr0 * H + hx4];
        float4 b0 = *(const float4*)(xp + xr1 * H + hx);
        float  b4 = xp[xr1 * H + hx4];
        float4 c0 = *(const float4*)(xp + xr2 * H + hx);
        float  c4 = xp[xr2 * H + hx4];

        float ra[5] = {a0.x, a0.y, a0.z, a0.w, a4};
        float rb[5] = {b0.x, b0.y, b0.z, b0.w, b4};
        float rc[5] = {c0.x, c0.y, c0.z, c0.w, c4};

        float* op = out + (size_t)p * PLANE_OUT;
        #pragma unroll
        for (int j = 0; j < 4; ++j) {
            float v0 = ra[j] * wt[0][j].x + ra[j+1] * wt[0][j].y
                     + rb[j] * wt[0][j].z + rb[j+1] * wt[0][j].w + bv[0][j];
            float v1 = rb[j] * wt[1][j].x + rb[j+1] * wt[1][j].y
                     + rc[j] * wt[1][j].z + rc[j+1] * wt[1][j].w + bv[1][j];
            if (h0 + j <= 510) {
                if (wv0) op[(size_t)w0 * OH + h0 + j] = v0;
                if (wv1) op[(size_t)w1 * OH + h0 + j] = v1;
            }
        }
    }
}

// Zero out row 0 (cols 0..510) and col 0 (rows 1..510) of each plane.
__global__ __launch_bounds__(256)
void zero_borders(float* __restrict__ out) {
    int i = blockIdx.x * 256 + threadIdx.x;     // 0 .. 1020
    int plane = blockIdx.y;
    float* op = out + (size_t)plane * PLANE_OUT;
    if (i < OH) {
        op[i] = 0.0f;                           // row 0
    } else if (i < OH + OW - 1) {
        int w = i - OH + 1;                     // 1..510
        op[(size_t)w * OH] = 0.0f;              // col 0
    }
}

extern "C" void kernel_launch(void* const* d_in, const int* in_sizes, int n_in,
                              void* d_out, int out_size, void* d_ws, size_t ws_size,
                              hipStream_t stream) {
    const float* x       = (const float*)d_in[0];
    const float* weights = (const float*)d_in[1];
    const float* bias    = (const float*)d_in[2];
    float*       out     = (float*)d_out;

    int planes = in_sizes[0] / PLANE_IN;        // 256
    int groups = (planes + PPG - 1) / PPG;      // 16

    dim3 gz((OH + OW - 1 + 255) / 256, planes);
    zero_borders<<<gz, 256, 0, stream>>>(out);

    dim3 grid(2 * 64, groups);                  // 128 tiles x 16 plane-groups
    lc_conv2x2_v2<<<grid, 256, 0, stream>>>(x, weights, bias, out, planes);
}

// Round 3
// 202.060 us; speedup vs baseline: 1.4940x; 1.1111x over previous
//
#include <hip/hip_runtime.h>

// Locally-connected 2x2 conv, unshared weights.
// x: [256 planes, 512, 512] f32; weights: [511*511, 4]; bias: [511*511]
// out: [256, 511, 511]; out row 0 / col 0 are zero.
// neuron index = 511*w + h == flat in-plane output index.
//
// v3: one thread = one col x TWO output rows (x middle row reused in reg).
// blockIdx.x = plane (fastest) -> 256 consecutive blocks share the same
// 10KB weights/bias tile (L2 hit after first). No per-thread loops -> max MLP.

constexpr int W = 512;
constexpr int H = 512;
constexpr int OW = 511;
constexpr int OH = 511;
constexpr int PLANE_OUT = OW * OH;      // 261121
constexpr int PLANE_IN  = W * H;        // 262144

__global__ __launch_bounds__(256)
void lc_conv2x2_v3(const float* __restrict__ x,
                   const float4* __restrict__ weights,
                   const float* __restrict__ bias,
                   float* __restrict__ out) {
    const int p    = blockIdx.x;              // plane (fastest -> weight reuse)
    const int tile = blockIdx.y;              // 0..509
    const int t    = tile >> 1;               // row-pair 0..254
    const int half = tile & 1;                // col half
    const int h    = (half << 8) | threadIdx.x;   // 0..511
    const int w0   = 2 * t + 1;               // 1,3,...,509
    const int w1   = w0 + 1;                  // 2,4,...,510

    if (h > 510) return;                      // col 511 doesn't exist

    float* op = out + (size_t)p * PLANE_OUT;

    if (t == 0) op[h] = 0.0f;                 // output row 0 = zeros

    if (h == 0) {                             // output col 0 = zeros
        op[(size_t)w0 * OH] = 0.0f;
        op[(size_t)w1 * OH] = 0.0f;
        return;
    }

    const float* xp = x + (size_t)p * PLANE_IN;
    const int hm = h - 1;

    // 3 x-rows feed 2 output rows; middle row reused in registers.
    float a0 = xp[(w0 - 1) * H + hm];
    float a1 = xp[(w0 - 1) * H + h];
    float b0 = xp[w0 * H + hm];
    float b1 = xp[w0 * H + h];
    float c0 = xp[w1 * H + hm];
    float c1 = xp[w1 * H + h];

    const size_t g0 = (size_t)w0 * OH + h;    // neuron/out flat index row w0
    const size_t g1 = (size_t)w1 * OH + h;

    float4 wt0 = weights[g0];
    float4 wt1 = weights[g1];
    float  bv0 = bias[g0];
    float  bv1 = bias[g1];

    op[g0] = a0 * wt0.x + a1 * wt0.y + b0 * wt0.z + b1 * wt0.w + bv0;
    op[g1] = b0 * wt1.x + b1 * wt1.y + c0 * wt1.z + c1 * wt1.w + bv1;
}

extern "C" void kernel_launch(void* const* d_in, const int* in_sizes, int n_in,
                              void* d_out, int out_size, void* d_ws, size_t ws_size,
                              hipStream_t stream) {
    const float*  x       = (const float*)d_in[0];
    const float4* weights = (const float4*)d_in[1];
    const float*  bias    = (const float*)d_in[2];
    float*        out     = (float*)d_out;

    int planes = in_sizes[0] / PLANE_IN;      // 256
    dim3 grid(planes, 510);                   // plane fastest; 255 row-pairs x 2 halves
    lc_conv2x2_v3<<<grid, 256, 0, stream>>>(x, weights, bias, out);
}